// Round 11
// baseline (213.726 us; speedup 1.0000x reference)
//
#include <hip/hip_runtime.h>
#include <hip/hip_bf16.h>

#define B_ 2
#define S_ 2048
#define D_ 1024
#define H_ 16
#define DH 64
#define M_ (B_*S_)   // 4096
#define NT_ (S_/64)  // 32 q tiles per (b,h)

using bf16x8 = __attribute__((ext_vector_type(8))) __bf16;
using bf16x4 = __attribute__((ext_vector_type(4))) __bf16;
using f32x4  = __attribute__((ext_vector_type(4))) float;

__device__ __forceinline__ int swz(int row) { return ((row ^ (row >> 3)) & 7) << 3; }

__device__ __forceinline__ void glds16(const __bf16* g, __bf16* l) {
#if __has_builtin(__builtin_amdgcn_global_load_lds)
  __builtin_amdgcn_global_load_lds(
      (const __attribute__((address_space(1))) unsigned int*)g,
      (__attribute__((address_space(3))) unsigned int*)l, 16, 0, 0);
#else
  *(bf16x8*)l = *(const bf16x8*)g;
#endif
}

// ---------- prep: conv_x (blocks 0..2047) + conv_w (blocks 2048..2815) -----
#define NBX 2048
__global__ __launch_bounds__(256) void prep(
    const float* __restrict__ x, const float* __restrict__ Wq,
    const float* __restrict__ Wk, const float* __restrict__ Wv,
    __bf16* __restrict__ xb, __bf16* __restrict__ wt) {
  int bid = blockIdx.x, tid = threadIdx.x;
  if (bid < NBX) {
    int idx = bid * 256 + tid;
    int m = idx >> 7, k = (idx & 127) * 8;
    float4 a = *(const float4*)&x[(size_t)m * D_ + k];
    float4 b = *(const float4*)&x[(size_t)m * D_ + k + 4];
    bf16x8 o;
    o[0]=(__bf16)a.x; o[1]=(__bf16)a.y; o[2]=(__bf16)a.z; o[3]=(__bf16)a.w;
    o[4]=(__bf16)b.x; o[5]=(__bf16)b.y; o[6]=(__bf16)b.z; o[7]=(__bf16)b.w;
    *(bf16x8*)&xb[(size_t)m * D_ + (k & ~63) + ((k & 63) ^ swz(m))] = o;
    return;
  }
  int wb = bid - NBX;
  int z = wb >> 8;
  int kt = (wb & 255) >> 4, nt = wb & 15;
  const float* __restrict__ W = (z == 0) ? Wq : (z == 1) ? Wk : Wv;
  __bf16* __restrict__ Wt = wt + (size_t)z * D_ * D_;
  __shared__ __bf16 Lt[64 * 66];
  int k0 = kt * 64, n0 = nt * 64;
  #pragma unroll
  for (int i = 0; i < 4; ++i) {
    int f4 = i * 256 + tid;
    int r = f4 >> 4, c4 = (f4 & 15) * 4;
    float4 v = *(const float4*)&W[(size_t)(k0 + r) * D_ + n0 + c4];
    Lt[(c4 + 0) * 66 + r] = (__bf16)v.x;
    Lt[(c4 + 1) * 66 + r] = (__bf16)v.y;
    Lt[(c4 + 2) * 66 + r] = (__bf16)v.z;
    Lt[(c4 + 3) * 66 + r] = (__bf16)v.w;
  }
  __syncthreads();
  #pragma unroll
  for (int i = 0; i < 2; ++i) {
    int idx = i * 256 + tid;
    int n = idx >> 3, kc = (idx & 7) * 8;
    int nf = n0 + n;
    bf16x8 o;
    #pragma unroll
    for (int j = 0; j < 8; ++j) o[j] = Lt[n * 66 + kc + j];
    *(bf16x8*)&Wt[(size_t)nf * D_ + k0 + (kc ^ swz(nf))] = o;
  }
}

// ---------- QKV GEMM: 256x256, BK=64, 8 waves, 4-phase counted-vmcnt -------
#define BM 256
#define BN 256
#define BK 64
#define NKT (D_/BK)  // 16
#define NWG 192

__global__ __launch_bounds__(512) void qkv_gemm(
    const __bf16* __restrict__ xb, const __bf16* __restrict__ wt,
    const float* __restrict__ bq, const float* __restrict__ bk,
    const float* __restrict__ bv, __bf16* __restrict__ qk,
    __bf16* __restrict__ vt) {
  int flat = blockIdx.x;
  int sid = (flat & 7) * (NWG / 8) + (flat >> 3);   // bijective XCD swizzle
  int z = sid >> 6;
  int rem = sid & 63;
  int my = rem >> 2, nx = rem & 3;

  const __bf16* __restrict__ Wt = wt + (size_t)z * D_ * D_;
  const float* __restrict__ bias = (z == 0) ? bq : (z == 1) ? bk : bv;
  const float scale = (z == 0) ? 0.125f : 1.0f;   // 1/sqrt(64) into Q

  __shared__ __bf16 SB[4][BM * BK];   // [0..1]=A dbuf, [2..3]=B dbuf; 128KB

  int tid = threadIdx.x, lane = tid & 63, w = tid >> 6;
  const int g = lane >> 4, ql = lane & 15;
  int m0 = my * BM, n0 = nx * BN;
  int wr = (w >> 2) * 128;
  int wc = (w & 3) * 64;

  f32x4 acc[8][4] = {};
  bf16x8 bfr[4];

#define STAGE2(buf, kt, p)                                                    \
  {                                                                           \
    int k0 = (kt) * BK;                                                       \
    _Pragma("unroll")                                                         \
    for (int q = 0; q < 2; ++q) {                                             \
      int c = 2 * (p) + q;                                                    \
      int e = ((c & 3) * 512 + tid) * 8;                                      \
      int row = e >> 6, col = e & 63;                                         \
      if (c < 4) glds16(&xb[(size_t)(m0 + row) * D_ + k0 + col], &SB[buf][e]);\
      else glds16(&Wt[(size_t)(n0 + row) * D_ + k0 + col], &SB[2 + (buf)][e]);\
    }                                                                         \
  }

#define DSB(buf, kk)                                                          \
  {                                                                           \
    _Pragma("unroll")                                                         \
    for (int ni = 0; ni < 4; ++ni) {                                          \
      int col = wc + ni * 16 + ql;                                            \
      bfr[ni] = *(const bf16x8*)&SB[2 + (buf)][col * 64 +                     \
                (((kk) * 32 + g * 8) ^ swz(col))];                            \
    }                                                                         \
  }

#define DSA4(buf, kk, mh, af)                                                 \
  {                                                                           \
    _Pragma("unroll")                                                         \
    for (int mi = 0; mi < 4; ++mi) {                                          \
      int row = wr + ((mh) * 4 + mi) * 16 + ql;                               \
      af[mi] = *(const bf16x8*)&SB[buf][row * 64 +                            \
               (((kk) * 32 + g * 8) ^ swz(row))];                             \
    }                                                                         \
  }

#define MFMA16(af, mh)                                                        \
  {                                                                           \
    __builtin_amdgcn_s_setprio(1);                                            \
    _Pragma("unroll")                                                         \
    for (int mi = 0; mi < 4; ++mi)                                            \
      _Pragma("unroll")                                                       \
      for (int ni = 0; ni < 4; ++ni)                                          \
        acc[(mh) * 4 + mi][ni] = __builtin_amdgcn_mfma_f32_16x16x32_bf16(     \
            af[mi], bfr[ni], acc[(mh) * 4 + mi][ni], 0, 0, 0);                \
    __builtin_amdgcn_s_setprio(0);                                            \
  }

  #pragma unroll
  for (int p = 0; p < 4; ++p) STAGE2(0, 0, p);

  for (int t = 0; t < NKT; ++t) {
    int cb = t & 1, nb = cb ^ 1;
    bool pf = (t + 1 < NKT);
    bf16x8 af[4];
    if (pf) STAGE2(nb, t + 1, 0);
    __builtin_amdgcn_sched_barrier(0);
    if (pf) { asm volatile("s_waitcnt vmcnt(2)" ::: "memory"); }
    else    { asm volatile("s_waitcnt vmcnt(0)" ::: "memory"); }
    __builtin_amdgcn_sched_barrier(0);
    __builtin_amdgcn_s_barrier();
    __builtin_amdgcn_sched_barrier(0);
    DSB(cb, 0);
    DSA4(cb, 0, 0, af);
    MFMA16(af, 0);
    if (pf) STAGE2(nb, t + 1, 1);
    DSA4(cb, 0, 1, af);
    __builtin_amdgcn_s_barrier();
    MFMA16(af, 1);
    if (pf) STAGE2(nb, t + 1, 2);
    DSB(cb, 1);
    DSA4(cb, 1, 0, af);
    __builtin_amdgcn_s_barrier();
    MFMA16(af, 0);
    if (pf) STAGE2(nb, t + 1, 3);
    DSA4(cb, 1, 1, af);
    __builtin_amdgcn_s_barrier();
    MFMA16(af, 1);
  }
  __syncthreads();
#undef STAGE2
#undef DSB
#undef DSA4
#undef MFMA16

  // ---- epilogue via LDS transpose; all stores b128-coalesced ----
  __bf16* Lt = &SB[0][0];
  const int b = m0 >> 11;
  const int sbase = m0 & 2047;
  if (z == 2) {
    #pragma unroll
    for (int mi = 0; mi < 8; ++mi) {
      #pragma unroll
      for (int ni = 0; ni < 4; ++ni) {
        int nl = wc + ni * 16 + ql;
        int ml = wr + mi * 16 + g * 4;
        float bv_ = bias[n0 + nl];
        bf16x4 p4;
        #pragma unroll
        for (int r = 0; r < 4; ++r) p4[r] = (__bf16)(acc[mi][ni][r] + bv_);
        *(bf16x4*)&Lt[nl * 256 + (ml ^ ((nl & 7) << 3))] = p4;
      }
    }
    __syncthreads();
    #pragma unroll
    for (int i = 0; i < 16; ++i) {
      int gi = i * 512 + tid;
      int n = gi >> 5, mg = (gi & 31) * 8;
      bf16x8 v = *(const bf16x8*)&Lt[n * 256 + (mg ^ ((n & 7) << 3))];
      int col = n0 + n, hh = col >> 6, dh = col & 63;
      *(bf16x8*)&vt[((size_t)(b * H_ + hh) * DH + dh) * S_ + sbase + mg] = v;
    }
  } else {
    __bf16* __restrict__ out = qk + (size_t)z * M_ * D_;
    #pragma unroll
    for (int mi = 0; mi < 8; ++mi) {
      #pragma unroll
      for (int ni = 0; ni < 4; ++ni) {
        int nl = wc + ni * 16 + ql;
        float bv_ = bias[n0 + nl];
        #pragma unroll
        for (int r = 0; r < 4; ++r) {
          int ml = wr + mi * 16 + g * 4 + r;
          Lt[ml * 256 + (nl ^ ((ml & 7) << 3))] =
              (__bf16)((acc[mi][ni][r] + bv_) * scale);
        }
      }
    }
    __syncthreads();
    #pragma unroll
    for (int i = 0; i < 16; ++i) {
      int gi = i * 512 + tid;
      int ml = gi >> 5, rest = gi & 31;
      int hh = rest >> 3, cg = (rest & 7) * 8;
      int n = hh * 64 + cg;
      bf16x8 v = *(const bf16x8*)&Lt[ml * 256 + (n ^ ((ml & 7) << 3))];
      int col = n0 + n, ho = col >> 6, dh = col & 63;
      *(bf16x8*)&out[((size_t)(b * H_ + ho) * S_ + sbase + ml) * DH + dh] = v;
    }
  }
}

// ---------- flash attention: un-paired, longest-first, swapped QK^T --------
__global__ __launch_bounds__(256) void attn(
    const __bf16* __restrict__ Q, const __bf16* __restrict__ K,
    const __bf16* __restrict__ VT, float* __restrict__ out) {
  __shared__ __bf16 Kl[64 * 64];
  __shared__ __bf16 Vt[64 * 64];
  __shared__ __bf16 Pl[4][16 * 64];

  int tid = threadIdx.x, lane = tid & 63, w = tid >> 6;
  int qt = NT_ - 1 - blockIdx.x;           // longest blocks dispatch first
  int h = blockIdx.y, b = blockIdx.z;
  int q0 = qt * 64;
  size_t base = ((size_t)(b * H_ + h)) * S_ * DH;
  const __bf16* __restrict__ Qg = Q + base;
  const __bf16* __restrict__ Kg = K + base;
  const __bf16* __restrict__ VTg = VT + base;   // [dh][s]

  const int g = lane >> 4, ql = lane & 15;
  const int qbase = q0 + w * 16;

  bf16x8 aq[2];
  #pragma unroll
  for (int kk = 0; kk < 2; ++kk)
    aq[kk] = *(const bf16x8*)&Qg[(size_t)(qbase + ql) * DH + kk * 32 + g * 8];

  f32x4 accO[4] = {};
  float m_reg = -1e30f, l_reg = 0.f;

  const int ktmax = qt;   // kv tiles 0..qt

  bf16x8 kreg[2], vreg[2];
  #pragma unroll
  for (int i = 0; i < 2; ++i) {
    int e = (i * 256 + tid) * 8;
    kreg[i] = *(const bf16x8*)&Kg[(size_t)(e >> 6) * DH + (e & 63)];
    vreg[i] = *(const bf16x8*)&VTg[(size_t)(e >> 6) * S_ + (e & 63)];
  }

  for (int kt = 0; kt <= ktmax; ++kt) {
    int kv0 = kt * 64;
    #pragma unroll
    for (int i = 0; i < 2; ++i) {
      int e = (i * 256 + tid) * 8;
      int rrow = e >> 6, cc = e & 63;
      *(bf16x8*)&Kl[rrow * 64 + (cc ^ swz(rrow))] = kreg[i];
      *(bf16x8*)&Vt[rrow * 64 + (cc ^ swz(rrow))] = vreg[i];
    }
    __syncthreads();

    if (kt < ktmax) {
      int kvn = kv0 + 64;
      #pragma unroll
      for (int i = 0; i < 2; ++i) {
        int e = (i * 256 + tid) * 8;
        kreg[i] = *(const bf16x8*)&Kg[(size_t)(kvn + (e >> 6)) * DH + (e & 63)];
        vreg[i] = *(const bf16x8*)&VTg[(size_t)(e >> 6) * S_ + kvn + (e & 63)];
      }
    }

    // ---- QK^T (S^T = mfma(K, Q)) ----
    f32x4 sfT[4];
    __builtin_amdgcn_s_setprio(1);
    #pragma unroll
    for (int f = 0; f < 4; ++f) {
      f32x4 zz = {};
      int row = f * 16 + ql;
      int sr = swz(row);
      #pragma unroll
      for (int kk = 0; kk < 2; ++kk) {
        bf16x8 ka = *(const bf16x8*)&Kl[row * 64 + ((kk * 32 + g * 8) ^ sr)];
        zz = __builtin_amdgcn_mfma_f32_16x16x32_bf16(ka, aq[kk], zz, 0, 0, 0);
      }
      sfT[f] = zz;
    }
    __builtin_amdgcn_s_setprio(0);

    if (kt == ktmax) {   // diagonal tile: causal mask
      int qg = qbase + ql;
      #pragma unroll
      for (int f = 0; f < 4; ++f)
        #pragma unroll
        for (int r = 0; r < 4; ++r)
          if (kv0 + f * 16 + g * 4 + r > qg) sfT[f][r] = -1e30f;
    }

    // ---- softmax (per-q in-register; q = ql per lane) ----
    float mx = sfT[0][0];
    #pragma unroll
    for (int f = 0; f < 4; ++f)
      #pragma unroll
      for (int r = 0; r < 4; ++r) mx = fmaxf(mx, sfT[f][r]);
    mx = fmaxf(mx, __shfl_xor(mx, 16, 64));
    mx = fmaxf(mx, __shfl_xor(mx, 32, 64));
    float mnew = fmaxf(m_reg, mx);
    float alpha = __expf(m_reg - mnew);
    m_reg = mnew;
    float rs = 0.f;
    #pragma unroll
    for (int f = 0; f < 4; ++f)
      #pragma unroll
      for (int r = 0; r < 4; ++r) {
        float p = __expf(sfT[f][r] - mnew);
        sfT[f][r] = p;
        rs += p;
      }
    rs += __shfl_xor(rs, 16, 64);
    rs += __shfl_xor(rs, 32, 64);
    l_reg = l_reg * alpha + rs;

    const int key = (ql & 7) << 3;
    #pragma unroll
    for (int f = 0; f < 4; ++f)
      #pragma unroll
      for (int r = 0; r < 4; ++r)
        Pl[w][ql * 64 + ((f * 16 + g * 4 + r) ^ key)] = (__bf16)sfT[f][r];

    float ab[4];
    #pragma unroll
    for (int r = 0; r < 4; ++r) ab[r] = __shfl(alpha, g * 4 + r, 16);
    #pragma unroll
    for (int f = 0; f < 4; ++f)
      #pragma unroll
      for (int r = 0; r < 4; ++r) accO[f][r] *= ab[r];

    // ---- O += P V ----
    __builtin_amdgcn_s_setprio(1);
    #pragma unroll
    for (int kk = 0; kk < 2; ++kk) {
      bf16x8 pa = *(const bf16x8*)&Pl[w][ql * 64 + ((kk * 32 + g * 8) ^ key)];
      #pragma unroll
      for (int f = 0; f < 4; ++f) {
        int vrow = f * 16 + ql;
        bf16x8 vb = *(const bf16x8*)&Vt[vrow * 64 + ((kk * 32 + g * 8) ^ swz(vrow))];
        accO[f] = __builtin_amdgcn_mfma_f32_16x16x32_bf16(pa, vb, accO[f], 0, 0, 0);
      }
    }
    __builtin_amdgcn_s_setprio(0);
    __syncthreads();
  }

  // ---- output ----
  float lr[4];
  #pragma unroll
  for (int r = 0; r < 4; ++r) lr[r] = __shfl(l_reg, g * 4 + r, 16);
  #pragma unroll
  for (int f = 0; f < 4; ++f) {
    int dh = f * 16 + ql;
    #pragma unroll
    for (int r = 0; r < 4; ++r) {
      int qg = qbase + g * 4 + r;
      out[((size_t)(b * S_ + qg)) * D_ + h * DH + dh] = accO[f][r] / lr[r];
    }
  }
}

extern "C" void kernel_launch(void* const* d_in, const int* in_sizes, int n_in,
                              void* d_out, int out_size, void* d_ws, size_t ws_size,
                              hipStream_t stream) {
  const float* x  = (const float*)d_in[0];
  const float* Wq = (const float*)d_in[1];
  const float* bq = (const float*)d_in[2];
  const float* Wk = (const float*)d_in[3];
  const float* bk = (const float*)d_in[4];
  const float* Wv = (const float*)d_in[5];
  const float* bv = (const float*)d_in[6];
  float* out = (float*)d_out;

  __bf16* xb  = (__bf16*)d_ws;             // 8 MB
  __bf16* wt  = xb + (size_t)M_ * D_;      // 6 MB
  __bf16* qkv = wt + (size_t)3 * D_ * D_;  // 24 MB: Q, K, V^T
  __bf16* wsq = qkv;
  __bf16* wsk = qkv + (size_t)M_ * D_;
  __bf16* vtg = qkv + (size_t)2 * M_ * D_;

  prep<<<NBX + 768, 256, 0, stream>>>(x, Wq, Wk, Wv, xb, wt);
  qkv_gemm<<<NWG, 512, 0, stream>>>(xb, wt, bq, bk, bv, qkv, vtg);
  attn<<<dim3(NT_, H_, B_), 256, 0, stream>>>(wsq, wsk, vtg, out);
}